// Round 5
// baseline (390.199 us; speedup 1.0000x reference)
//
#include <hip/hip_runtime.h>

// LSTM: B=8192, T=512, H=32. Block = 256 thr (4 waves) owns TWO groups
// (32 batches); grid 256 -> 1 block/CU, 1 wave/SIMD, 4 lockstep waves.
// Each iteration = two WINDOWS: A computes group A step t, B computes group B
// step t. B-frags for a window are ds_read-PREFETCHED at the top of the
// previous window (one barrier in between): LDS latency + lgkm drain hide
// under the other group's ~300cy of compute — unlike R0, where the read sat
// exposed right after the barrier inside the recurrence chain.
// Lockstep: all 4 waves run identical streams on the 4 SIMDs -> barriers
// convoy nothing (R0's loss was cross-block drift).
// Per-window math = R0 verbatim (absmax 2^-10): transposed MFMA D = W'*h via
// mfma_f32_16x16x32_f16, wave w owns tiles 2w,2w+1 -> 2 cells/lane
// (units 8q+2w+tt, batch c). FP16 2-term h (hi+lo planes, hi/lo MFMAs made
// INDEPENDENT with zero-C + fp32 add to cut chain). K-perm pi_q(j)=j XOR 2q.
// Gates pre-scaled by -log2e (i,f,o) / +2log2e (g): 10 exp2 + 4 rcp/window.
// Weights & per-cell consts shared between groups (same registers).

#define TT 512
#define HH 32
#define L2E 1.44269504088896340736f
#define XROW 132   // x tile row stride (floats)

typedef _Float16 f16x8 __attribute__((ext_vector_type(8)));
typedef __fp16 fp16x2 __attribute__((ext_vector_type(2)));
typedef float f32x4 __attribute__((ext_vector_type(4)));
typedef float f32x2 __attribute__((ext_vector_type(2)));

__device__ __forceinline__ float fastrcp(float x) { return __builtin_amdgcn_rcpf(x); }
__device__ __forceinline__ float exp2f_(float x) { return __builtin_amdgcn_exp2f(x); }

__launch_bounds__(256, 1)
__global__ void lstm_kernel(const float* __restrict__ x,
                            const float* __restrict__ W_ih,
                            const float* __restrict__ W_hh,
                            const float* __restrict__ b_ih,
                            const float* __restrict__ b_hh,
                            const float* __restrict__ W_fc,
                            const float* __restrict__ b_fc,
                            float* __restrict__ out) {
    // h planes per group: [grp][parity][qblk(4)*128 + batch(16)*8 + slot(8)]
    __shared__ _Float16 hhp[2][2][512];   // h hi
    __shared__ _Float16 hlp[2][2][512];   // h lo
    __shared__ float xbuf[2][16 * XROW];  // per-group x chunk (128 steps)

    const int tid  = threadIdx.x;
    const int lane = tid & 63;
    const int w    = tid >> 6;        // wave 0..3: owns tiles 2w, 2w+1
    const int c    = lane & 15;       // batch-in-group (MFMA n); also A m-row
    const int q    = lane >> 4;       // quad: k-block 8q; unit-block 8q
    const int base = blockIdx.x * 32; // 32 batches per block (2 groups)

    // ---- A-fragments (weights) tiles 2w+tt, single fp16, k-perm j^2q ----
    const int gate = c & 3;
    const float asc = (gate == 2) ? (2.0f * L2E) : (-L2E);
    const int wrow0 = gate * 32 + 8 * (c >> 2);
    f16x8 wah[2];
    #pragma unroll
    for (int tt = 0; tt < 2; ++tt) {
        const int t8 = 2 * w + tt;
        #pragma unroll
        for (int j = 0; j < 8; ++j) {
            const int u = 8 * q + (j ^ (2 * q));
            wah[tt][j] = (_Float16)(W_hh[(wrow0 + t8) * HH + u] * asc);
        }
    }

    // ---- per-cell consts: cell tt = (unit 8q + 2w + tt, batch c) ----
    f32x4 wihs[2], bcs[2];
    #pragma unroll
    for (int tt = 0; tt < 2; ++tt) {
        const int u = 8 * q + 2 * w + tt;
        #pragma unroll
        for (int r = 0; r < 4; ++r) {
            const float sc = (r == 2) ? (2.0f * L2E) : (-L2E);
            wihs[tt][r] = W_ih[32 * r + u] * sc;
            bcs[tt][r]  = (b_ih[32 * r + u] + b_hh[32 * r + u]) * sc;
        }
    }

    // B-frag read offset (fp16 units); h write offset with k-perm (even slot)
    const int rdo = q * 128 + c * 8;
    const int wro = rdo + ((2 * w) ^ (2 * q));

    // ---- x staging: per group 16 rows x 128 floats, 2 float4/thread ----
    const int xrow = tid >> 4;            // 0..15
    const int xj4  = (tid & 15) * 4;      // 0..60
    auto stage = [&](int g, int tc) {
        #pragma unroll
        for (int s = 0; s < 2; ++s) {
            const float4 v = *(const float4*)
                &x[(size_t)(base + 16 * g + xrow) * TT + tc + xj4 + 64 * s];
            *(float4*)&xbuf[g][xrow * XROW + xj4 + 64 * s] = v;
        }
    };
    stage(0, 0);
    stage(1, 0);
    __syncthreads();

    // ---- per-group recurrent state ----
    f32x2 csA = {0.f, 0.f}, csB = {0.f, 0.f};
    f32x4 aiA[2], aiB[2];
    {
        const float xa = xbuf[0][c * XROW];
        const float xb = xbuf[1][c * XROW];
        aiA[0] = wihs[0] * xa + bcs[0]; aiA[1] = wihs[1] * xa + bcs[1];
        aiB[0] = wihs[0] * xb + bcs[0]; aiB[1] = wihs[1] * xb + bcs[1];
    }
    f16x8 bhA = (f16x8)(_Float16)0.f, blA = bhA;   // h0 = 0 -> zero frags
    f16x8 bhB = bhA, blB = bhA;

    // window: compute group g's step t using pre-read frags; write h(t+1);
    // prepare ai for t+1. (R0 STEP math verbatim, MFMAs de-chained.)
    auto window = [&](int g, f32x4* ai, const f16x8& bh, const f16x8& bl,
                      f32x2& cs2, int t) {
        const f32x4 z = {0.f, 0.f, 0.f, 0.f};
        f32x4 a0 = __builtin_amdgcn_mfma_f32_16x16x32_f16(wah[0], bh, ai[0], 0, 0, 0);
        f32x4 a1 = __builtin_amdgcn_mfma_f32_16x16x32_f16(wah[1], bh, ai[1], 0, 0, 0);
        const f32x4 b0 = __builtin_amdgcn_mfma_f32_16x16x32_f16(wah[0], bl, z, 0, 0, 0);
        const f32x4 b1 = __builtin_amdgcn_mfma_f32_16x16x32_f16(wah[1], bl, z, 0, 0, 0);
        a0 += b0;
        a1 += b1;
        f32x2 Ei, Ef, G, Eo;
        Ei.x = exp2f_(a0[0]); Ei.y = exp2f_(a1[0]);
        Ef.x = exp2f_(a0[1]); Ef.y = exp2f_(a1[1]);
        G.x  = exp2f_(a0[2]); G.y  = exp2f_(a1[2]);
        Eo.x = exp2f_(a0[3]); Eo.y = exp2f_(a1[3]);
        const f32x2 one = {1.f, 1.f};
        const f32x2 aig = (one + Ei) * (G + one);
        const f32x2 af  = one + Ef;
        const f32x2 num = cs2 * aig + (G - one) * af;
        const f32x2 den = af * aig;
        f32x2 rc; rc.x = fastrcp(den.x); rc.y = fastrcp(den.y);
        const f32x2 cn = num * rc;
        cs2 = cn;
        f32x2 yc = cn * (2.0f * L2E);
        yc.x = __builtin_amdgcn_fmed3f(yc.x, -60.f, 60.f);
        yc.y = __builtin_amdgcn_fmed3f(yc.y, -60.f, 60.f);
        f32x2 C; C.x = exp2f_(yc.x); C.y = exp2f_(yc.y);
        const f32x2 hden = (C + one) * (one + Eo);
        f32x2 hr; hr.x = fastrcp(hden.x); hr.y = fastrcp(hden.y);
        const f32x2 hv = (C - one) * hr;
        union PK { fp16x2 v; int i; _Float16 e[2]; } ph, pl;
        ph.v = __builtin_amdgcn_cvt_pkrtz(hv.x, hv.y);
        pl.v = __builtin_amdgcn_cvt_pkrtz(hv.x - (float)ph.e[0],
                                          hv.y - (float)ph.e[1]);
        const int WP = (t + 1) & 1;
        *(int*)&hhp[g][WP][wro] = ph.i;
        *(int*)&hlp[g][WP][wro] = pl.i;
        // next step's a-init (garbage at chunk edge; boundary recompute fixes)
        const float xn = xbuf[g][c * XROW + ((t + 1) & 127)];
        ai[0] = wihs[0] * xn + bcs[0];
        ai[1] = wihs[1] * xn + bcs[1];
    };

    #pragma unroll 1
    for (int t = 0; t < TT; ++t) {
        if (t && (t & 127) == 0) {
            // restage both groups' x chunks; recompute ai from fresh chunk
            stage(0, t);
            stage(1, t);
            __syncthreads();
            const float xa = xbuf[0][c * XROW];
            const float xb = xbuf[1][c * XROW];
            aiA[0] = wihs[0] * xa + bcs[0]; aiA[1] = wihs[1] * xa + bcs[1];
            aiB[0] = wihs[0] * xb + bcs[0]; aiB[1] = wihs[1] * xb + bcs[1];
        }
        // ---- window A(t): prefetch B(t) frags, then group-A math ----
        if (t) {
            bhB = *(const f16x8*)&hhp[1][t & 1][rdo];   // written in B(t-1),
            blB = *(const f16x8*)&hlp[1][t & 1][rdo];   // barrier since
            __builtin_amdgcn_sched_barrier(0);          // keep issue early
        }
        window(0, aiA, bhA, blA, csA, t);
        __syncthreads();
        // ---- window B(t): prefetch A(t+1) frags, then group-B math ----
        bhA = *(const f16x8*)&hhp[0][(t + 1) & 1][rdo]; // written in A(t),
        blA = *(const f16x8*)&hlp[0][(t + 1) & 1][rdo]; // barrier since
        __builtin_amdgcn_sched_barrier(0);
        window(1, aiB, bhB, blB, csB, t);
        __syncthreads();
    }
    // Final h(512) in parity-0 planes of both groups; loop ended with barrier.

    // ---- head: out[b] = h_T @ W_fc^T + b_fc (k-perm aware); wave w<2 ----
    if (w < 2 && lane < 16) {
        float s = b_fc[0];
        #pragma unroll
        for (int u = 0; u < 32; ++u) {
            const int qb = u >> 3;
            const int off = qb * 128 + lane * 8 + ((u & 7) ^ (2 * qb));
            s += ((float)hhp[w][0][off] + (float)hlp[w][0][off]) * W_fc[u];
        }
        out[base + 16 * w + lane] = s;
    }
}

extern "C" void kernel_launch(void* const* d_in, const int* in_sizes, int n_in,
                              void* d_out, int out_size, void* d_ws, size_t ws_size,
                              hipStream_t stream) {
    const float* x    = (const float*)d_in[0];
    const float* W_ih = (const float*)d_in[1];
    const float* W_hh = (const float*)d_in[2];
    const float* b_ih = (const float*)d_in[3];
    const float* b_hh = (const float*)d_in[4];
    const float* W_fc = (const float*)d_in[5];
    const float* b_fc = (const float*)d_in[6];
    float* out = (float*)d_out;

    const int B = 8192;
    lstm_kernel<<<B / 32, 256, 0, stream>>>(x, W_ih, W_hh, b_ih, b_hh,
                                            W_fc, b_fc, out);
}

// Round 6
// 280.305 us; speedup vs baseline: 1.3921x; 1.3921x over previous
//
#include <hip/hip_runtime.h>

// LSTM: B=8192, T=512, H=32. R6 = R3 structure + R0 LDS layout.
// Block = 512 threads (8 waves) per 16-batch group; 512 blocks -> 2 blocks/CU,
// 16 waves/CU (4/SIMD) — R3's measured-best 62% issue duty.
// Fix vs R3 (236us): R3's [16][40] fp16 plane had 8-way write conflicts
// (bank=4(5c+q) mod 32; 46M conflict-cyc). Here: R0's k-perm plane
// [parity][q*128 + c*8 + slot], slot = w XOR 2q -> write bank 4c + ((w^2q)>>1)
// = 2-way (free); reads b128 at q*128+c*8 are the R0-proven pattern (6.3M).
// Transposed MFMA D = W'*h via mfma_f32_16x16x32_f16. Wave w owns tile w:
// D at lane (c,q) reg r = gate r of cell (unit 8q+w, batch c) -> ONE cell/lane.
// B-frag element j = h[unit 8q + (j^2q)][batch c] (k-perm on A-frag to match).
// FP16 2-term h (hi+lo planes); hi/lo MFMAs DE-CHAINED (zero-C + f32 add)
// to cut ~20cy off the recurrence chain. Gates pre-scaled by -log2e (i,f,o)
// / +2log2e (g); per-lane scalar cell math: 5 exp2 + 2 rcp.
// s_setprio(1) over MFMA+cell burst (T5; 4 waves/SIMD at drifting phases).

#define TT 512
#define HH 32
#define L2E 1.44269504088896340736f
#define XROW 132   // x row stride (floats): bank 4c+t mod 32 -> 2-way (free)

typedef _Float16 f16x8 __attribute__((ext_vector_type(8)));
typedef float f32x4 __attribute__((ext_vector_type(4)));

__device__ __forceinline__ float fastrcp(float x) { return __builtin_amdgcn_rcpf(x); }
__device__ __forceinline__ float exp2f_(float x) { return __builtin_amdgcn_exp2f(x); }

__launch_bounds__(512, 4)
__global__ void lstm_kernel(const float* __restrict__ x,
                            const float* __restrict__ W_ih,
                            const float* __restrict__ W_hh,
                            const float* __restrict__ b_ih,
                            const float* __restrict__ b_hh,
                            const float* __restrict__ W_fc,
                            const float* __restrict__ b_fc,
                            float* __restrict__ out) {
    // h planes: [parity][qblk(4)*128 + batch(16)*8 + slot(8)] fp16 (k-perm)
    __shared__ _Float16 hhp[2][512];   // h hi
    __shared__ _Float16 hlp[2][512];   // h lo
    __shared__ float xbuf[16 * XROW];  // x chunk: 16 batches x 128 steps

    const int tid  = threadIdx.x;
    const int lane = tid & 63;
    const int w    = tid >> 6;        // wave 0..7 = tile index
    const int c    = lane & 15;       // batch (MFMA n); also A m-row
    const int q    = lane >> 4;       // quad: k-block 8q; unit-block 8q
    const int base = blockIdx.x * 16;

    // ---- A-fragment (weights) for tile w, single fp16, k-perm j^2q ----
    const int gate = c & 3;
    const float asc = (gate == 2) ? (2.0f * L2E) : (-L2E);
    const int wrow0 = gate * 32 + 8 * (c >> 2);
    f16x8 wa;
    #pragma unroll
    for (int j = 0; j < 8; ++j) {
        const int u = 8 * q + (j ^ (2 * q));
        wa[j] = (_Float16)(W_hh[(wrow0 + w) * HH + u] * asc);
    }

    // ---- per-cell consts: this lane's cell = (unit 8q + w, batch c) ----
    const int u = 8 * q + w;
    f32x4 wih, bcs;
    #pragma unroll
    for (int r = 0; r < 4; ++r) {
        const float sc = (r == 2) ? (2.0f * L2E) : (-L2E);
        wih[r] = W_ih[32 * r + u] * sc;
        bcs[r] = (b_ih[32 * r + u] + b_hh[32 * r + u]) * sc;
    }

    // B-frag read offset (fp16 units); this lane's h write slot (k-perm)
    const int rdo = q * 128 + c * 8;
    const int wro = rdo + (w ^ (2 * q));

    // ---- zero parity-0 planes (h0 = 0) ----
    for (int i = tid; i < 512; i += 512) {
        hhp[0][i] = (_Float16)0.f;
        hlp[0][i] = (_Float16)0.f;
    }

    // ---- stage x chunk 0: 16 rows x 128 floats = 512 float4, 1/thread ----
    const int xr  = tid >> 5;             // 0..15
    const int xc4 = (tid & 31) * 4;       // 0..124
    {
        const float4 v = *(const float4*)&x[(size_t)(base + xr) * TT + xc4];
        *(float4*)&xbuf[xr * XROW + xc4] = v;
    }

    float cs = 0.f;                        // c-state for this lane's cell
    f32x4 ai;                              // a-init (wih*x + bias) for step t

    #pragma unroll 1
    for (int t = 0; t < TT; ++t) {
        const int RP = t & 1;
        if ((t & 127) == 0) {
            if (t) {
                // old-chunk reads all completed before prior step's barrier
                const float4 v = *(const float4*)&x[(size_t)(base + xr) * TT + t + xc4];
                *(float4*)&xbuf[xr * XROW + xc4] = v;
            }
            __syncthreads();               // covers staging (and init at t=0)
            const float xc = xbuf[c * XROW];
            ai = wih * xc + bcs;
        }
        // post-barrier critical path: 2x b128 read -> 2 independent MFMAs
        const f16x8 BH = *(const f16x8*)&hhp[RP][rdo];
        const f16x8 BL = *(const f16x8*)&hlp[RP][rdo];
        __builtin_amdgcn_s_setprio(1);
        const f32x4 z = {0.f, 0.f, 0.f, 0.f};
        const f32x4 a0 = __builtin_amdgcn_mfma_f32_16x16x32_f16(wa, BH, ai, 0, 0, 0);
        const f32x4 a1 = __builtin_amdgcn_mfma_f32_16x16x32_f16(wa, BL, z, 0, 0, 0);
        const float xn = xbuf[c * XROW + ((t + 1) & 127)];  // prefetch next x
        const f32x4 a = a0 + a1;
        const float Ei = exp2f_(a[0]);
        const float Ef = exp2f_(a[1]);
        const float G  = exp2f_(a[2]);
        const float Eo = exp2f_(a[3]);
        const float aig = (1.f + Ei) * (G + 1.f);
        const float af  = 1.f + Ef;
        const float num = cs * aig + (G - 1.f) * af;
        const float den = af * aig;
        const float cn  = num * fastrcp(den);
        cs = cn;
        const float ycv = __builtin_amdgcn_fmed3f(cn * (2.0f * L2E), -60.f, 60.f);
        const float C   = exp2f_(ycv);
        const float hden = (C + 1.f) * (1.f + Eo);
        const float hv   = (C - 1.f) * fastrcp(hden);
        __builtin_amdgcn_s_setprio(0);
        const _Float16 ph = (_Float16)hv;
        const _Float16 pl = (_Float16)(hv - (float)ph);
        hhp[RP ^ 1][wro] = ph;             // k-perm slot: bank 4c+((w^2q)>>1)
        hlp[RP ^ 1][wro] = pl;             // -> 2-way only (free)
        ai = wih * xn + bcs;               // next step's a-init (pre-barrier)
        __syncthreads();
    }
    // T=512 even -> final h in parity-0 planes; loop ended with a barrier.

    // ---- head: out[b] = h_T @ W_fc^T + b_fc (k-perm aware; wave 0) ----
    if (tid < 16) {
        float s = b_fc[0];
        #pragma unroll
        for (int uu = 0; uu < 32; ++uu) {
            const int qb = uu >> 3;
            const int off = qb * 128 + tid * 8 + ((uu & 7) ^ (2 * qb));
            s += ((float)hhp[0][off] + (float)hlp[0][off]) * W_fc[uu];
        }
        out[base + tid] = s;
    }
}

extern "C" void kernel_launch(void* const* d_in, const int* in_sizes, int n_in,
                              void* d_out, int out_size, void* d_ws, size_t ws_size,
                              hipStream_t stream) {
    const float* x    = (const float*)d_in[0];
    const float* W_ih = (const float*)d_in[1];
    const float* W_hh = (const float*)d_in[2];
    const float* b_ih = (const float*)d_in[3];
    const float* b_hh = (const float*)d_in[4];
    const float* W_fc = (const float*)d_in[5];
    const float* b_fc = (const float*)d_in[6];
    float* out = (float*)d_out;

    const int B = 8192;
    lstm_kernel<<<B / 16, 512, 0, stream>>>(x, W_ih, W_hh, b_ih, b_hh,
                                            W_fc, b_fc, out);
}

// Round 7
// 264.801 us; speedup vs baseline: 1.4736x; 1.0585x over previous
//
#include <hip/hip_runtime.h>

// LSTM: B=8192, T=512, H=32. R7 = R0 champion (208us) + BLOCK ANTI-PHASE SKEW.
// Block = 256 threads (4 waves) per 16-batch group; 512 blocks -> 2 blocks/CU,
// 8 waves/CU (2/SIMD from different blocks).
// R0's duty was 52%: wall 977cy/step ~ issue(508) + chain(~450) -> the two
// co-resident blocks run IN-PHASE (launched together, identical cadence, no
// cross-sync) so their stalls and issue never overlap. Fix: blocks pair on a
// CU as (bid, bid+256) under 8-XCD round-robin -> class (bid>>8)&1; class-1
// sleeps ~512cy ONCE before the loop. The skew persists (no global sync ever
// re-aligns blocks), putting the pair in anti-phase: A's chain-stall is filled
// by B's issue burst. s_setprio(1) over the post-barrier dependent burst (T5
// applies exactly when co-SIMD waves are at different phases).
// Also: hi/lo MFMAs de-chained (zero-C + f32 add; -20cy chain, R6-verified).
// All math/layout = R0 verbatim (absmax 2^-10): transposed MFMA D = W'*h via
// mfma_f32_16x16x32_f16, wave w owns tiles 2w,2w+1 -> 2 cells/lane; FP16
// 2-term h (hi+lo planes); K-perm pi_q(j)=j XOR 2q; gates pre-scaled by
// -log2e (i,f,o) / +2log2e (g); 10 exp2 + 4 rcp per wave-step.

#define TT 512
#define HH 32
#define L2E 1.44269504088896340736f

typedef _Float16 f16x8 __attribute__((ext_vector_type(8)));
typedef __fp16 fp16x2 __attribute__((ext_vector_type(2)));
typedef float f32x4 __attribute__((ext_vector_type(4)));
typedef float f32x2 __attribute__((ext_vector_type(2)));

__device__ __forceinline__ float fastrcp(float x) { return __builtin_amdgcn_rcpf(x); }
__device__ __forceinline__ float exp2f_(float x) { return __builtin_amdgcn_exp2f(x); }

#define XROW 132   // x tile row stride (floats): bank (4c+t) mod 32 -> 2-way

__launch_bounds__(256, 2)
__global__ void lstm_kernel(const float* __restrict__ x,
                            const float* __restrict__ W_ih,
                            const float* __restrict__ W_hh,
                            const float* __restrict__ b_ih,
                            const float* __restrict__ b_hh,
                            const float* __restrict__ W_fc,
                            const float* __restrict__ b_fc,
                            float* __restrict__ out) {
    // h planes: [parity][qblk(4)][batch(16)][j(8)] fp16 = 512 per parity
    __shared__ _Float16 hhp[2][512];   // h hi
    __shared__ _Float16 hlp[2][512];   // h lo
    __shared__ float xbuf[16 * XROW];

    const int tid  = threadIdx.x;
    const int lane = tid & 63;
    const int w    = tid >> 6;        // wave id 0..3: owns tiles 2w, 2w+1
    const int c    = lane & 15;       // batch (MFMA n); also A m-row
    const int q    = lane >> 4;       // quad: k-block 8q; unit-block 8q
    const int base = blockIdx.x * 16;

    // ---- A-fragments (weights) for tiles 2w+tt, single fp16 ----
    // k-slot j of block q holds unit 8q + (j XOR 2q).
    const int gate = c & 3;
    const float asc = (gate == 2) ? (2.0f * L2E) : (-L2E);
    const int wrow0 = gate * 32 + 8 * (c >> 2);
    f16x8 wah[2];
    #pragma unroll
    for (int tt = 0; tt < 2; ++tt) {
        const int t8 = 2 * w + tt;
        #pragma unroll
        for (int j = 0; j < 8; ++j) {
            const int u = 8 * q + (j ^ (2 * q));
            wah[tt][j] = (_Float16)(W_hh[(wrow0 + t8) * HH + u] * asc);
        }
    }

    // ---- per-cell consts: cell tt = (unit 8q + 2w + tt, batch c) ----
    f32x4 wihs[2], bcs[2];
    #pragma unroll
    for (int tt = 0; tt < 2; ++tt) {
        const int u = 8 * q + 2 * w + tt;
        #pragma unroll
        for (int r = 0; r < 4; ++r) {
            const float sc = (r == 2) ? (2.0f * L2E) : (-L2E);
            wihs[tt][r] = W_ih[32 * r + u] * sc;
            bcs[tt][r]  = (b_ih[32 * r + u] + b_hh[32 * r + u]) * sc;
        }
    }

    // ---- init parity-0 h planes to zero (h0 = 0) ----
    #pragma unroll
    for (int i = tid; i < 512; i += 256) {
        hhp[0][i] = (_Float16)0.f;
        hlp[0][i] = (_Float16)0.f;
    }

    f32x2 cs2 = {0.f, 0.f};          // c-state for cells tt=0,1

    // x staging: 16 rows x 128 floats, 512 float4 over 256 threads (2 each)
    const int xrow = tid >> 4;
    const int xj4  = (tid & 15) * 4;

    // B-frag read offset (fp16 units); h write offset with k-perm (even slot)
    const int rdo = q * 128 + c * 8;
    const int wro = rdo + ((2 * w) ^ (2 * q));

    // ---- ANTI-PHASE SKEW: co-resident pair on a CU = (bid, bid+256) under
    // 8-XCD round-robin of the 512-block grid. Class-1 delays ~512cy once;
    // the offset persists for all 512 steps (no cross-block sync exists).
    if ((blockIdx.x >> 8) & 1) {
        __builtin_amdgcn_s_sleep(8);   // 8*64 = 512 cycles
    }

    #define STEP(t, RP, WP)                                                   \
    {                                                                         \
        const f16x8 bh = *(const f16x8*)&hhp[RP][rdo];                        \
        const f16x8 bl = *(const f16x8*)&hlp[RP][rdo];                        \
        const float xc = xbuf[c * XROW + ((t) & 127)];                        \
        __builtin_amdgcn_s_setprio(1);                                        \
        const f32x4 z = {0.f, 0.f, 0.f, 0.f};                                 \
        f32x4 acc[2];                                                         \
        _Pragma("unroll")                                                     \
        for (int tt = 0; tt < 2; ++tt) {                                      \
            const f32x4 a0 = __builtin_amdgcn_mfma_f32_16x16x32_f16(          \
                wah[tt], bh, wihs[tt] * xc + bcs[tt], 0, 0, 0);               \
            const f32x4 a1 = __builtin_amdgcn_mfma_f32_16x16x32_f16(          \
                wah[tt], bl, z, 0, 0, 0);                                     \
            acc[tt] = a0 + a1;                                                \
        }                                                                     \
        f32x2 Ei, Ef, G, Eo;                                                  \
        Ei.x = exp2f_(acc[0][0]); Ei.y = exp2f_(acc[1][0]);                   \
        Ef.x = exp2f_(acc[0][1]); Ef.y = exp2f_(acc[1][1]);                   \
        G.x  = exp2f_(acc[0][2]); G.y  = exp2f_(acc[1][2]);                   \
        Eo.x = exp2f_(acc[0][3]); Eo.y = exp2f_(acc[1][3]);                   \
        const f32x2 one = {1.f, 1.f};                                         \
        const f32x2 aig = (one + Ei) * (G + one);                             \
        const f32x2 af  = one + Ef;                                           \
        const f32x2 num = cs2 * aig + (G - one) * af;                         \
        const f32x2 den = af * aig;                                           \
        f32x2 rc; rc.x = fastrcp(den.x); rc.y = fastrcp(den.y);               \
        const f32x2 cn = num * rc;                                            \
        cs2 = cn;                                                             \
        f32x2 yc = cn * (2.0f * L2E);                                         \
        yc.x = __builtin_amdgcn_fmed3f(yc.x, -60.f, 60.f);                    \
        yc.y = __builtin_amdgcn_fmed3f(yc.y, -60.f, 60.f);                    \
        f32x2 C; C.x = exp2f_(yc.x); C.y = exp2f_(yc.y);                      \
        const f32x2 hden = (C + one) * (one + Eo);                            \
        f32x2 hr; hr.x = fastrcp(hden.x); hr.y = fastrcp(hden.y);             \
        const f32x2 hv = (C - one) * hr;                                      \
        __builtin_amdgcn_s_setprio(0);                                        \
        union { fp16x2 v; int i; _Float16 e[2]; } ph, pl;                     \
        ph.v = __builtin_amdgcn_cvt_pkrtz(hv.x, hv.y);                        \
        pl.v = __builtin_amdgcn_cvt_pkrtz(hv.x - (float)ph.e[0],              \
                                          hv.y - (float)ph.e[1]);             \
        *(int*)&hhp[WP][wro] = ph.i;                                          \
        *(int*)&hlp[WP][wro] = pl.i;                                          \
        __syncthreads();                                                      \
    }

    for (int t = 0; t < TT; t += 2) {
        if ((t & 127) == 0) {
            #pragma unroll
            for (int s = 0; s < 2; ++s) {
                const float4 v = *(const float4*)&x[(base + xrow) * TT + t + xj4 + 64 * s];
                *(float4*)&xbuf[xrow * XROW + xj4 + 64 * s] = v;
            }
            __syncthreads();
        }
        STEP(t,     0, 1);   // read parity 0 (h(t)), write parity 1 (h(t+1))
        STEP(t + 1, 1, 0);   // read parity 1, write parity 0
    }
    // T even -> final h(512) is in parity-0 planes; loop ended with a barrier.

    // ---- head: out[b] = h_T @ W_fc^T + b_fc (k-perm aware) ----
    if (tid < 16) {
        float s = b_fc[0];
        #pragma unroll
        for (int u = 0; u < 32; ++u) {
            const int qb = u >> 3;
            const int off = qb * 128 + tid * 8 + ((u & 7) ^ (2 * qb));
            s += ((float)hhp[0][off] + (float)hlp[0][off]) * W_fc[u];
        }
        out[base + tid] = s;
    }
}

extern "C" void kernel_launch(void* const* d_in, const int* in_sizes, int n_in,
                              void* d_out, int out_size, void* d_ws, size_t ws_size,
                              hipStream_t stream) {
    const float* x    = (const float*)d_in[0];
    const float* W_ih = (const float*)d_in[1];
    const float* W_hh = (const float*)d_in[2];
    const float* b_ih = (const float*)d_in[3];
    const float* b_hh = (const float*)d_in[4];
    const float* W_fc = (const float*)d_in[5];
    const float* b_fc = (const float*)d_in[6];
    float* out = (float*)d_out;

    const int B = 8192;
    lstm_kernel<<<B / 16, 256, 0, stream>>>(x, W_ih, W_hh, b_ih, b_hh,
                                            W_fc, b_fc, out);
}